// Round 11
// baseline (160.976 us; speedup 1.0000x reference)
//
#include <hip/hip_runtime.h>
#include <cstdint>

#define TT 2048
#define NH 16
#define NKV 8
#define HD 128
// 1/sqrt(128) * log2(e)  (softmax computed in exp2 domain)
#define SCALE_L2E 0.12751743f
// static softmax max bound: ||q||=||k||=sqrt(128) (unit rmsnorm weights), RoPE is a
// rotation => |score|*log2(e) <= sqrt(128)*log2(e) = 16.33; margin -> 16.5. P in (0,1].
#define SM_M2 16.5f

typedef unsigned short u16;
typedef unsigned int u32;
typedef u16 u16x8 __attribute__((ext_vector_type(8)));
typedef u32 u32x2 __attribute__((ext_vector_type(2)));
typedef __bf16 bf16x8 __attribute__((ext_vector_type(8)));
typedef float f32x4 __attribute__((ext_vector_type(4)));
typedef float f32x16 __attribute__((ext_vector_type(16)));

__device__ inline u16 f2bf(float x){
  u32 u = __builtin_bit_cast(u32, x);
  u = (u + 0x7fffu + ((u >> 16) & 1u)) >> 16;
  return (u16)u;
}
__device__ inline float bf2f(u16 h){
  return __builtin_bit_cast(float, (u32)h << 16);
}
__device__ inline bf16x8 as_bf(u16x8 v){ return __builtin_bit_cast(bf16x8, v); }

__device__ inline void gl_lds16(const void* g, void* l){
  typedef __attribute__((address_space(1))) const void gv_t;
  typedef __attribute__((address_space(3))) void lv_t;
  __builtin_amdgcn_global_load_lds((gv_t*)g, (lv_t*)l, 16, 0, 0);
}

// ---------------- cast fp32 -> bf16 ----------------
__global__ void cast_f32_bf16(const float* __restrict__ in, u16* __restrict__ out, int n8){
  int i = blockIdx.x * blockDim.x + threadIdx.x;
  if (i < n8){
    const float4* p = (const float4*)(in + (size_t)i * 8);
    float4 a = p[0], b = p[1];
    u16x8 o = { f2bf(a.x), f2bf(a.y), f2bf(a.z), f2bf(a.w),
                f2bf(b.x), f2bf(b.y), f2bf(b.z), f2bf(b.w) };
    *(u16x8*)(out + (size_t)i * 8) = o;
  }
}

// ---------------- transpose + cast: in [R][C] f32 -> out [C][R] bf16 ----------------
__global__ void transpose_cast(const float* __restrict__ in, u16* __restrict__ out, int R, int C){
  __shared__ float tile[64][65];
  int bx = blockIdx.x * 64;  // col base (source)
  int by = blockIdx.y * 64;  // row base (source)
  int tid = threadIdx.x;
  #pragma unroll
  for (int i = 0; i < 4; ++i){
    int idx = i * 256 + tid;           // 0..1023
    int r = idx >> 4, c4 = (idx & 15) * 4;
    float4 v = *(const float4*)&in[(size_t)(by + r) * C + bx + c4];
    tile[r][c4] = v.x; tile[r][c4 + 1] = v.y; tile[r][c4 + 2] = v.z; tile[r][c4 + 3] = v.w;
  }
  __syncthreads();
  #pragma unroll
  for (int i = 0; i < 2; ++i){
    int idx = i * 256 + tid;           // 0..511
    int cc = idx >> 3, s8 = (idx & 7) * 8;
    u16x8 o;
    #pragma unroll
    for (int j = 0; j < 8; ++j) o[j] = f2bf(tile[s8 + j][cc]);
    *(u16x8*)&out[(size_t)(bx + cc) * R + by + s8] = o;
  }
}

// ---------------- lookahead-pipelined GEMM: C[M,N] = A[M,K] * B^T ----------------
template<bool F32OUT>
__global__ __launch_bounds__(512, 2) void gemm8p(const u16* __restrict__ A, const u16* __restrict__ B,
                                                 void* __restrict__ Cv, int Klen,
                                                 int lda, int ldb, int ldc, size_t zstride){
  extern __shared__ u16 smem[];     // 3 bufs x (A 128*64 + B 256*64) u16
  const int tid = threadIdx.x;
  const int wv = tid >> 6, ln = tid & 63;
  const int lg = ln >> 4, l15 = ln & 15;
  const int wr = wv >> 2, wc = wv & 3;          // 2 x 4 wave grid
  const int nbx = gridDim.x;
  const int orig = blockIdx.x + nbx * blockIdx.y;
  const int cpx = (nbx * gridDim.y) >> 3;
  const int swz = (orig & 7) * cpx + (orig >> 3);
  const int m0 = (swz / nbx) * 128, n0 = (swz % nbx) * 256;
  const int Kofs = blockIdx.z * Klen;
  const u16* Ab0 = A + (size_t)m0 * lda + Kofs;
  const u16* Bb0 = B + (size_t)n0 * ldb + Kofs;
  f32x4 acc[4][4] = {};

  auto stage = [&](int sbuf, int kt, int part){
    u16* base = smem + sbuf * 24576;
    if (part == 0){
      const u16* Ak = Ab0 + kt * 64;
      #pragma unroll
      for (int it = 0; it < 2; ++it){
        int idx = it * 512 + tid;
        int r = idx >> 3, sl = idx & 7, g = sl ^ (r & 7);
        gl_lds16(Ak + (size_t)r * lda + g * 8, base + (it * 512 + wv * 64) * 8);
      }
      const u16* Bk = Bb0 + kt * 64;
      { int idx = tid; int r = idx >> 3, sl = idx & 7, g = sl ^ (r & 7);
        gl_lds16(Bk + (size_t)r * ldb + g * 8, base + (8192 + wv * 64 * 8)); }
    } else {
      const u16* Bk = Bb0 + kt * 64;
      #pragma unroll
      for (int it = 1; it < 4; ++it){
        int idx = it * 512 + tid;
        int r = idx >> 3, sl = idx & 7, g = sl ^ (r & 7);
        gl_lds16(Bk + (size_t)r * ldb + g * 8, base + (8192 + (it * 512 + wv * 64) * 8));
      }
    }
  };

  bf16x8 a0[4], b0[4], a1[4], b1[4];
  auto ldfrags = [&](const u16* lA, bf16x8* af, bf16x8* bf, int kk){
    const u16* lB = lA + 8192;
    #pragma unroll
    for (int mm = 0; mm < 4; mm++){
      int ra = wr * 64 + mm * 16 + l15;
      int sl = (kk * 4 + lg) ^ (ra & 7);
      af[mm] = as_bf(*(const u16x8*)&lA[(ra * 8 + sl) * 8]);
    }
    #pragma unroll
    for (int nn = 0; nn < 4; nn++){
      int cb = wc * 64 + nn * 16 + l15;
      int sl = (kk * 4 + lg) ^ (cb & 7);
      bf[nn] = as_bf(*(const u16x8*)&lB[(cb * 8 + sl) * 8]);
    }
  };
  auto mfma16 = [&](bf16x8* af, bf16x8* bf){
    __builtin_amdgcn_s_setprio(1);
    #pragma unroll
    for (int mm = 0; mm < 4; mm++)
      #pragma unroll
      for (int nn = 0; nn < 4; nn++)
        acc[mm][nn] = __builtin_amdgcn_mfma_f32_16x16x32_bf16(af[mm], bf[nn], acc[mm][nn], 0, 0, 0);
    __builtin_amdgcn_s_setprio(0);
  };

  const int nk = Klen / 64;
  stage(0, 0, 0); stage(0, 0, 1);
  stage(1, 1, 0); stage(1, 1, 1);
  asm volatile("s_waitcnt vmcnt(6)" ::: "memory");
  asm volatile("s_barrier" ::: "memory");
  ldfrags(smem, a0, b0, 0);

  for (int kt = 0; kt < nk; ++kt){
    const u16* lA = smem + (kt % 3) * 24576;
    ldfrags(lA, a1, b1, 1);
    if (kt + 2 < nk) stage((kt + 2) % 3, kt + 2, 0);
    mfma16(a0, b0);
    if (kt + 2 < nk)      asm volatile("s_waitcnt vmcnt(3)" ::: "memory");
    else if (kt + 1 < nk) asm volatile("s_waitcnt vmcnt(0)" ::: "memory");
    asm volatile("s_barrier" ::: "memory");
    if (kt + 1 < nk)
      ldfrags(smem + ((kt + 1) % 3) * 24576, a0, b0, 0);
    if (kt + 2 < nk) stage((kt + 2) % 3, kt + 2, 1);
    mfma16(a1, b1);
    asm volatile("s_barrier" ::: "memory");
  }
  #pragma unroll
  for (int mm = 0; mm < 4; mm++)
    #pragma unroll
    for (int nn = 0; nn < 4; nn++){
      int grow0 = m0 + wr * 64 + mm * 16 + lg * 4;
      int gcol  = n0 + wc * 64 + nn * 16 + l15;
      #pragma unroll
      for (int r = 0; r < 4; r++){
        float v = acc[mm][nn][r];
        if (F32OUT) ((float*)Cv + blockIdx.z * zstride)[(size_t)(grow0 + r) * ldc + gcol] = v;
        else        ((u16*)Cv)[(size_t)(grow0 + r) * ldc + gcol] = f2bf(v);
      }
    }
}

// ---------------- fp32 add (split-K reduce) ----------------
__global__ void add_f32(const float* __restrict__ a, const float* __restrict__ b,
                        float* __restrict__ o, int n4){
  int i = blockIdx.x * blockDim.x + threadIdx.x;
  if (i < n4){
    float4 x = ((const float4*)a)[i], y = ((const float4*)b)[i];
    float4 z = { x.x + y.x, x.y + y.y, x.z + y.z, x.w + y.w };
    ((float4*)o)[i] = z;
  }
}

// ---------------- RMSNorm + RoPE for Q and K; one wave per (token, head-slot) ----------------
__global__ void rmsnorm_rope(const u16* __restrict__ QKV, const int* __restrict__ pos,
                             const float* __restrict__ qw, const float* __restrict__ kw,
                             u16* __restrict__ Qr, u16* __restrict__ Kr){
  int gw = (blockIdx.x * blockDim.x + threadIdx.x) >> 6;
  int ln = threadIdx.x & 63;
  int t = gw / 24, idx = gw % 24;         // 16 Q heads + 8 K heads
  if (t >= TT) return;
  bool isq = idx < NH;
  int head = isq ? idx : idx - NH;
  const u16* src = QKV + (size_t)t * 4096 + (isq ? head * HD : 2048 + head * HD);
  const float* wgt = isq ? qw : kw;
  float x0 = bf2f(src[ln]), x1 = bf2f(src[ln + 64]);
  float ss = x0 * x0 + x1 * x1;
  #pragma unroll
  for (int off = 32; off; off >>= 1) ss += __shfl_xor(ss, off);
  float r = rsqrtf(ss * (1.0f / 128.0f) + 1e-6f);
  float xn0 = x0 * r * wgt[ln], xn1 = x1 * r * wgt[ln + 64];
  float inv = exp2f(-(float)ln * 0.311430758895690f);  // log2(1e6)/64
  float ang = (float)pos[t] * inv;
  float c = cosf(ang), s = sinf(ang);
  float o0 = xn0 * c - xn1 * s;
  float o1 = xn1 * c + xn0 * s;
  u16* dst = isq ? (Qr + (size_t)t * 2048 + head * HD) : (Kr + (size_t)t * 1024 + head * HD);
  dst[ln]      = f2bf(o0);
  dst[ln + 64] = f2bf(o1);
}

// ---------------- V transpose: QKV[t][3072 + kh*128 + d] -> Vt[kh][d][t] ----------------
__global__ void v_transpose(const u16* __restrict__ QKV, u16* __restrict__ Vt){
  __shared__ u16 tile[64][72];
  int kh = blockIdx.z;
  int d0 = blockIdx.y * 64;
  int t0 = blockIdx.x * 64;
  int tid = threadIdx.x;
  #pragma unroll
  for (int it = 0; it < 2; ++it){
    int idx = it * 256 + tid;          // 0..511
    int tr = idx >> 3, seg = idx & 7;
    *(u16x8*)&tile[tr][seg * 8] =
      *(const u16x8*)(QKV + (size_t)(t0 + tr) * 4096 + 3072 + kh * HD + d0 + seg * 8);
  }
  __syncthreads();
  #pragma unroll
  for (int it = 0; it < 2; ++it){
    int idx = it * 256 + tid;
    int dr = idx >> 3, seg = idx & 7;
    u16x8 v;
    #pragma unroll
    for (int j = 0; j < 8; j++) v[j] = tile[seg * 8 + j][dr];
    *(u16x8*)(Vt + ((size_t)kh * HD + d0 + dr) * 2048 + t0 + seg * 8) = v;
  }
}

// ---------------- causal GQA flash attention: balanced split-chunk blocks ----------------
// 512 blocks = (p = bx&15, half = bx>>4) x 16 heads; each block stages 16-17 K/V tiles:
//   half0: chunk c1=p tiles [0,p] then chunk c2=31-p tiles [0,16-p)   (17 tiles)
//   half1: chunk c2 tiles [16-p, 32-p)                                (16 tiles)
// => per-block work is UNIFORM regardless of CU assignment (fixes the R10 imbalance).
// 8 waves: 0-3 S-role (QK^T+softmax+P), 4-7 PV-role; role=(qw=r&1, jp=r>>1).
// S: jp splits the 64-token tile (32 toks each). PV: jp splits the d-dim (64 each),
// so each PV wave sees ALL tokens => no cross-wave combine; asum computed redundantly.
// Static-max softmax => chunk partials additive: c1 (rows<1024) finishes in half0 and
// is written normalized mid-loop; c2 partials (fp32 O + row-sums) go to per-half
// buffers, merged by attn_norm. LDS 75776B => 2 blocks/CU.
__global__ __launch_bounds__(512, 4) void attn(const u16* __restrict__ Qr, const u16* __restrict__ Kr,
                                               const u16* __restrict__ Vt, u16* __restrict__ O,
                                               float* __restrict__ PB0, float* __restrict__ PB1,
                                               float* __restrict__ RS0, float* __restrict__ RS1){
  extern __shared__ u16 smem[];
  u16* Karea = smem;                   // [2][64tok*128d] u16
  u16* Varea = smem + 16384;           // [2][128d*64tok] u16
  u16* Parea = smem + 32768;           // [4 role][32 q][40] u16
  const int p = blockIdx.x & 15, half = blockIdx.x >> 4;
  const int h = blockIdx.y, kh = h >> 1;
  const int c1 = p, c2 = 31 - p;
  const int nst = half ? 16 : 17;
  const int tid = threadIdx.x, wv = tid >> 6, ln = tid & 63;
  const bool isS = wv < 4;
  const int role = wv & 3;
  const int qw = role & 1, jp = role >> 1;
  const int q5 = ln & 31, hb = ln >> 5;

  auto ktof = [&](int j)->int { return half ? (16 - p + j) : ((j <= p) ? j : j - p - 1); };
  auto chof = [&](int j)->int { return (half == 0 && j <= p) ? c1 : c2; };

  auto stage = [&](int j){
    if (j + 1 < nst){                          // K for iter j+1 -> buf (j+1)&1
      int kt = ktof(j + 1);
      u16* Kd = Karea + ((j + 1) & 1) * 8192;
      #pragma unroll
      for (int jj = 0; jj < 2; ++jj){
        int lin = jj * 512 + tid;
        int tok = lin >> 4, seg = lin & 15;
        gl_lds16(Kr + (size_t)(kt * 64 + tok) * 1024 + kh * HD + (seg ^ (tok & 7)) * 8,
                 Kd + (jj * 512 + wv * 64) * 8);
      }
    }
    if (j < nst){                              // V for iter j -> buf j&1 (used at j+1)
      int kt = ktof(j);
      u16* Vd = Varea + (j & 1) * 8192;
      #pragma unroll
      for (int jj = 0; jj < 2; ++jj){
        int lin = jj * 512 + tid;
        int d = lin >> 3, sl = lin & 7;
        gl_lds16(Vt + (size_t)kh * HD * 2048 + (size_t)d * 2048 + kt * 64 + (sl ^ (d & 7)) * 8,
                 Vd + (jj * 512 + wv * 64) * 8);
      }
    }
  };

  // prestage K[ktof(0)] into buf 0
  {
    int kt = ktof(0);
    #pragma unroll
    for (int jj = 0; jj < 2; ++jj){
      int lin = jj * 512 + tid;
      int tok = lin >> 4, seg = lin & 15;
      gl_lds16(Kr + (size_t)(kt * 64 + tok) * 1024 + kh * HD + (seg ^ (tok & 7)) * 8,
               Karea + (jj * 512 + wv * 64) * 8);
    }
  }

  const u16x8 ones_u = {0x3f80, 0x3f80, 0x3f80, 0x3f80, 0x3f80, 0x3f80, 0x3f80, 0x3f80};
  const bf16x8 onesf = as_bf(ones_u);

  if (isS){
    // ---------------- S role: QK^T + static-max softmax + P write ----------------
    bf16x8 qf[8];
    {
      int c0 = half ? c2 : c1;
      const u16* qp = Qr + (size_t)(c0 * 64 + qw * 32 + q5) * 2048 + h * HD + hb * 8;
      #pragma unroll
      for (int s = 0; s < 8; ++s) qf[s] = as_bf(*(const u16x8*)(qp + s * 16));
    }
    u16* Pq = Parea + role * 1280 + q5 * 40;
    for (int j = 0; j <= nst; ++j){
      __syncthreads();                         // top: K[j], V[j-1], P[j-1] visible
      stage(j);
      if (half == 0 && j == p + 1){            // chunk switch: reload Q for c2
        const u16* qp = Qr + (size_t)(c2 * 64 + qw * 32 + q5) * 2048 + h * HD + hb * 8;
        #pragma unroll
        for (int s = 0; s < 8; ++s) qf[s] = as_bf(*(const u16x8*)(qp + s * 16));
      }
      bool act = false, diag = false;
      f32x16 c = {};
      if (j < nst){
        int kt = ktof(j), ch = chof(j);
        int D0 = 32 * (2 * kt + jp) - 64 * ch - 32 * qw;
        act = (D0 <= 0); diag = (D0 == 0);
        if (act){
          const u16* Kb = Karea + (j & 1) * 8192;
          const int tokIdx = 32 * jp + q5;
          __builtin_amdgcn_s_setprio(1);
          #pragma unroll
          for (int s = 0; s < 8; ++s){
            int seg = (2 * s + hb) ^ (q5 & 7);
            bf16x8 kf = as_bf(*(const u16x8*)&Kb[tokIdx * 128 + seg * 8]);
            c = __builtin_amdgcn_mfma_f32_32x32x16_bf16(kf, qf[s], c, 0, 0, 0);
          }
          __builtin_amdgcn_s_setprio(0);
        }
      }
      asm volatile("s_barrier" ::: "memory");  // mid: PV done reading P[j-1]
      if (act){
        u32 pk[8];
        #pragma unroll
        for (int jj = 0; jj < 8; ++jj){
          float pv[2];
          #pragma unroll
          for (int e = 0; e < 2; ++e){
            int r = 2 * jj + e;
            int tok = (r & 3) + 8 * (r >> 2) + 4 * hb;
            float x = c[r] * SCALE_L2E - SM_M2;
            if (diag && tok > q5) x = -1e30f;
            pv[e] = exp2f(x);
          }
          pk[jj] = (__builtin_bit_cast(u32, pv[0]) >> 16) |
                   (__builtin_bit_cast(u32, pv[1]) & 0xffff0000u);
        }
        *(u32x2*)&Pq[hb * 4 +  0] = u32x2{pk[0], pk[1]};
        *(u32x2*)&Pq[hb * 4 +  8] = u32x2{pk[2], pk[3]};
        *(u32x2*)&Pq[hb * 4 + 16] = u32x2{pk[4], pk[5]};
        *(u32x2*)&Pq[hb * 4 + 24] = u32x2{pk[6], pk[7]};
      }
    }
  } else {
    // ---------------- PV role: P (prev iter) x V + row-sum; jp picks 64 d-dims ----------------
    f32x16 acc[2] = {};
    f32x16 asum = {};
    const u16* Pw0 = Parea + (qw + 0) * 1280;  // S role (qw, jp=0): toks 0..31
    const u16* Pw1 = Parea + (qw + 2) * 1280;  // S role (qw, jp=1): toks 32..63
    for (int j = 0; j <= nst; ++j){
      __syncthreads();                         // top
      stage(j);
      bool vis0 = false, vis1 = false;
      int ch = 0;
      if (j >= 1){
        int kt = ktof(j - 1); ch = chof(j - 1);
        vis0 = (32 * (2 * kt + 0) - 64 * ch - 32 * qw) <= 0;
        vis1 = (32 * (2 * kt + 1) - 64 * ch - 32 * qw) <= 0;
      }
      bf16x8 pf0 = {}, pf1 = {}, pf2 = {}, pf3 = {};
      if (vis0){
        pf0 = as_bf(*(const u16x8*)&Pw0[q5 * 40 + hb * 8]);
        pf1 = as_bf(*(const u16x8*)&Pw0[q5 * 40 + 16 + hb * 8]);
        if (vis1){
          pf2 = as_bf(*(const u16x8*)&Pw1[q5 * 40 + hb * 8]);
          pf3 = as_bf(*(const u16x8*)&Pw1[q5 * 40 + 16 + hb * 8]);
        }
        asm volatile("s_waitcnt lgkmcnt(0)" ::: "memory");
        __builtin_amdgcn_sched_barrier(0);
      }
      asm volatile("s_barrier" ::: "memory");  // mid: P reads done before S rewrites
      if (vis0){
        const u16* Vb = Varea + ((j - 1) & 1) * 8192;
        __builtin_amdgcn_s_setprio(1);
        asum = __builtin_amdgcn_mfma_f32_32x32x16_bf16(pf0, onesf, asum, 0, 0, 0);
        asum = __builtin_amdgcn_mfma_f32_32x32x16_bf16(pf1, onesf, asum, 0, 0, 0);
        #pragma unroll
        for (int db = 0; db < 2; ++db){
          int d = (jp * 2 + db) * 32 + q5;
          bf16x8 v0 = as_bf(*(const u16x8*)&Vb[d * 64 + ((0 + hb) ^ (d & 7)) * 8]);
          bf16x8 v1 = as_bf(*(const u16x8*)&Vb[d * 64 + ((2 + hb) ^ (d & 7)) * 8]);
          acc[db] = __builtin_amdgcn_mfma_f32_32x32x16_bf16(pf0, v0, acc[db], 0, 0, 0);
          acc[db] = __builtin_amdgcn_mfma_f32_32x32x16_bf16(pf1, v1, acc[db], 0, 0, 0);
        }
        if (vis1){
          asum = __builtin_amdgcn_mfma_f32_32x32x16_bf16(pf2, onesf, asum, 0, 0, 0);
          asum = __builtin_amdgcn_mfma_f32_32x32x16_bf16(pf3, onesf, asum, 0, 0, 0);
          #pragma unroll
          for (int db = 0; db < 2; ++db){
            int d = (jp * 2 + db) * 32 + q5;
            bf16x8 v2 = as_bf(*(const u16x8*)&Vb[d * 64 + ((4 + hb) ^ (d & 7)) * 8]);
            bf16x8 v3 = as_bf(*(const u16x8*)&Vb[d * 64 + ((6 + hb) ^ (d & 7)) * 8]);
            acc[db] = __builtin_amdgcn_mfma_f32_32x32x16_bf16(pf2, v2, acc[db], 0, 0, 0);
            acc[db] = __builtin_amdgcn_mfma_f32_32x32x16_bf16(pf3, v3, acc[db], 0, 0, 0);
          }
        }
        __builtin_amdgcn_s_setprio(0);
      }
      // ---- chunk c1 complete (half0): write normalized bf16, reset ----
      if (half == 0 && j == p + 1){
        #pragma unroll
        for (int r = 0; r < 16; ++r){
          int qrow = (r & 3) + 8 * (r >> 2) + 4 * hb;
          float rinv = 1.0f / asum[r];
          int qg = c1 * 64 + qw * 32 + qrow;
          #pragma unroll
          for (int db = 0; db < 2; ++db)
            O[(size_t)qg * 2048 + h * HD + (jp * 2 + db) * 32 + q5] = f2bf(acc[db][r] * rinv);
        }
        acc[0] = f32x16{}; acc[1] = f32x16{}; asum = f32x16{};
      }
    }
    // ---- epilogue: chunk c2 fp32 partial -> per-half buffers ----
    float* PB = half ? PB1 : PB0;
    float* RS = half ? RS1 : RS0;
    #pragma unroll
    for (int r = 0; r < 16; ++r){
      int qrow = (r & 3) + 8 * (r >> 2) + 4 * hb;
      int qg = c2 * 64 + qw * 32 + qrow;       // >= 1024
      size_t rb = (size_t)(qg - 1024) * 2048 + h * HD;
      #pragma unroll
      for (int db = 0; db < 2; ++db)
        PB[rb + (jp * 2 + db) * 32 + q5] = acc[db][r];
      if (jp == 0 && q5 == 0) RS[(qg - 1024) * 16 + h] = asum[r];
    }
  }
}

// ---------------- merge + normalize rows 1024..2047 ----------------
__global__ void attn_norm(const float* __restrict__ PB0, const float* __restrict__ PB1,
                          const float* __restrict__ RS0, const float* __restrict__ RS1,
                          u16* __restrict__ O){
  int idx = blockIdx.x * blockDim.x + threadIdx.x;   // over 1024*2048/8
  int rp = idx >> 8;            // row' 0..1023
  int col = (idx & 255) * 8;    // 0..2040
  int h = col >> 7;
  float rinv = 1.0f / (RS0[rp * 16 + h] + RS1[rp * 16 + h]);
  size_t base = (size_t)rp * 2048 + col;
  float4 a0 = *(const float4*)&PB0[base],     a1 = *(const float4*)&PB0[base + 4];
  float4 b0 = *(const float4*)&PB1[base],     b1 = *(const float4*)&PB1[base + 4];
  u16x8 o = { f2bf((a0.x + b0.x) * rinv), f2bf((a0.y + b0.y) * rinv),
              f2bf((a0.z + b0.z) * rinv), f2bf((a0.w + b0.w) * rinv),
              f2bf((a1.x + b1.x) * rinv), f2bf((a1.y + b1.y) * rinv),
              f2bf((a1.z + b1.z) * rinv), f2bf((a1.w + b1.w) * rinv) };
  *(u16x8*)&O[(size_t)(1024 + rp) * 2048 + col] = o;
}

extern "C" void kernel_launch(void* const* d_in, const int* in_sizes, int n_in,
                              void* d_out, int out_size, void* d_ws, size_t ws_size,
                              hipStream_t stream){
  const int*   positions = (const int*)d_in[0];
  const float* hidden    = (const float*)d_in[1];
  const float* wq        = (const float*)d_in[2];
  const float* wk        = (const float*)d_in[3];
  const float* wv        = (const float*)d_in[4];
  const float* wo        = (const float*)d_in[5];
  const float* qw        = (const float*)d_in[6];
  const float* kw        = (const float*)d_in[7];
  float* out = (float*)d_out;

  char* ws = (char*)d_ws;
  u16* hs   = (u16*)ws; ws += (size_t)2048 * 2048 * 2;
  u16* Wqkv = (u16*)ws; ws += (size_t)4096 * 2048 * 2;   // [4096][2048] = Wq^T | Wk^T | Wv^T
  u16* Wo   = (u16*)ws; ws += (size_t)2048 * 2048 * 2;   // [2048][2048] = wo^T
  u16* QKV  = (u16*)ws; ws += (size_t)2048 * 4096 * 2;   // [T][4096]
  u16* Qr   = (u16*)ws; ws += (size_t)2048 * 2048 * 2;   // [T][16][128]
  u16* Kr   = (u16*)ws; ws += (size_t)2048 * 1024 * 2;   // [T][8][128]
  u16* Vt   = (u16*)ws; ws += (size_t)8 * 128 * 2048 * 2; // [8][128][T]
  u16* O    = (u16*)ws;                                   // [T][2048]

  // attn partial buffers overlay regions dead after the QKV GEMM:
  float* PB0 = (float*)hs;                        // 8MB
  float* PB1 = (float*)Wqkv;                      // 8MB (first half of Wqkv)
  float* RS0 = (float*)(Wqkv + (size_t)4194304);  // 64KB
  float* RS1 = RS0 + 16384;                       // 64KB

  cast_f32_bf16<<<2048, 256, 0, stream>>>(hidden, hs, 2048 * 2048 / 8);
  transpose_cast<<<dim3(32, 32), 256, 0, stream>>>(wq, Wqkv, 2048, 2048);
  transpose_cast<<<dim3(16, 32), 256, 0, stream>>>(wk, Wqkv + (size_t)2048 * 2048, 2048, 1024);
  transpose_cast<<<dim3(16, 32), 256, 0, stream>>>(wv, Wqkv + (size_t)3072 * 2048, 2048, 1024);
  transpose_cast<<<dim3(32, 32), 256, 0, stream>>>(wo, Wo, 2048, 2048);

  // QKV = hs @ [Wq|Wk|Wv] : M=2048, N=4096, K=2048 ; 256 blocks, 144KB LDS, 1 blk/CU
  gemm8p<false><<<dim3(16, 16, 1), 512, 147456, stream>>>(hs, Wqkv, QKV, 2048, 2048, 2048, 4096, 0);

  rmsnorm_rope<<<2048 * 24 / 4, 256, 0, stream>>>(QKV, positions, qw, kw, Qr, Kr);
  v_transpose<<<dim3(32, 2, 8), 256, 0, stream>>>(QKV, Vt);

  // balanced attention: 512 blocks x 512 threads, 75776B LDS => 2 blocks/CU
  attn<<<dim3(32, 16), 512, 75776, stream>>>(Qr, Kr, Vt, O, PB0, PB1, RS0, RS1);
  attn_norm<<<1024, 256, 0, stream>>>(PB0, PB1, RS0, RS1, O);

  // out = O @ wo : split-K=2 (256 blocks), fp32 partials overlay dead QKV region
  float* p0 = (float*)QKV;
  gemm8p<true><<<dim3(8, 16, 2), 512, 147456, stream>>>(O, Wo, p0, 1024, 2048, 2048, 2048,
                                                        (size_t)2048 * 2048);
  add_f32<<<4096, 256, 0, stream>>>(p0, p0 + (size_t)2048 * 2048, out, 2048 * 2048 / 4);
}

// Round 12
// 154.209 us; speedup vs baseline: 1.0439x; 1.0439x over previous
//
#include <hip/hip_runtime.h>
#include <cstdint>

#define TT 2048
#define NH 16
#define NKV 8
#define HD 128
// 1/sqrt(128) * log2(e)  (softmax computed in exp2 domain)
#define SCALE_L2E 0.12751743f
// static softmax max bound: ||q||=||k||=sqrt(128) (unit rmsnorm weights), RoPE is a
// rotation => |score|*log2(e) <= sqrt(128)*log2(e) = 16.33; margin -> 16.5. P in (0,1].
#define SM_M2 16.5f

typedef unsigned short u16;
typedef unsigned int u32;
typedef u16 u16x8 __attribute__((ext_vector_type(8)));
typedef u32 u32x2 __attribute__((ext_vector_type(2)));
typedef __bf16 bf16x8 __attribute__((ext_vector_type(8)));
typedef float f32x4 __attribute__((ext_vector_type(4)));
typedef float f32x16 __attribute__((ext_vector_type(16)));

__device__ inline u16 f2bf(float x){
  u32 u = __builtin_bit_cast(u32, x);
  u = (u + 0x7fffu + ((u >> 16) & 1u)) >> 16;
  return (u16)u;
}
__device__ inline float bf2f(u16 h){
  return __builtin_bit_cast(float, (u32)h << 16);
}
__device__ inline bf16x8 as_bf(u16x8 v){ return __builtin_bit_cast(bf16x8, v); }

__device__ inline void gl_lds16(const void* g, void* l){
  typedef __attribute__((address_space(1))) const void gv_t;
  typedef __attribute__((address_space(3))) void lv_t;
  __builtin_amdgcn_global_load_lds((gv_t*)g, (lv_t*)l, 16, 0, 0);
}

// ---------------- cast fp32 -> bf16 ----------------
__global__ void cast_f32_bf16(const float* __restrict__ in, u16* __restrict__ out, int n8){
  int i = blockIdx.x * blockDim.x + threadIdx.x;
  if (i < n8){
    const float4* p = (const float4*)(in + (size_t)i * 8);
    float4 a = p[0], b = p[1];
    u16x8 o = { f2bf(a.x), f2bf(a.y), f2bf(a.z), f2bf(a.w),
                f2bf(b.x), f2bf(b.y), f2bf(b.z), f2bf(b.w) };
    *(u16x8*)(out + (size_t)i * 8) = o;
  }
}

// ---------------- transpose + cast: in [R][C] f32 -> out [C][R] bf16 ----------------
__global__ void transpose_cast(const float* __restrict__ in, u16* __restrict__ out, int R, int C){
  __shared__ float tile[64][65];
  int bx = blockIdx.x * 64;  // col base (source)
  int by = blockIdx.y * 64;  // row base (source)
  int tid = threadIdx.x;
  #pragma unroll
  for (int i = 0; i < 4; ++i){
    int idx = i * 256 + tid;           // 0..1023
    int r = idx >> 4, c4 = (idx & 15) * 4;
    float4 v = *(const float4*)&in[(size_t)(by + r) * C + bx + c4];
    tile[r][c4] = v.x; tile[r][c4 + 1] = v.y; tile[r][c4 + 2] = v.z; tile[r][c4 + 3] = v.w;
  }
  __syncthreads();
  #pragma unroll
  for (int i = 0; i < 2; ++i){
    int idx = i * 256 + tid;           // 0..511
    int cc = idx >> 3, s8 = (idx & 7) * 8;
    u16x8 o;
    #pragma unroll
    for (int j = 0; j < 8; ++j) o[j] = f2bf(tile[s8 + j][cc]);
    *(u16x8*)&out[(size_t)(bx + cc) * R + by + s8] = o;
  }
}

// ---------------- lookahead-pipelined GEMM: C[M,N] = A[M,K] * B^T ----------------
template<bool F32OUT>
__global__ __launch_bounds__(512, 2) void gemm8p(const u16* __restrict__ A, const u16* __restrict__ B,
                                                 void* __restrict__ Cv, int Klen,
                                                 int lda, int ldb, int ldc, size_t zstride){
  extern __shared__ u16 smem[];     // 3 bufs x (A 128*64 + B 256*64) u16
  const int tid = threadIdx.x;
  const int wv = tid >> 6, ln = tid & 63;
  const int lg = ln >> 4, l15 = ln & 15;
  const int wr = wv >> 2, wc = wv & 3;          // 2 x 4 wave grid
  const int nbx = gridDim.x;
  const int orig = blockIdx.x + nbx * blockIdx.y;
  const int cpx = (nbx * gridDim.y) >> 3;
  const int swz = (orig & 7) * cpx + (orig >> 3);
  const int m0 = (swz / nbx) * 128, n0 = (swz % nbx) * 256;
  const int Kofs = blockIdx.z * Klen;
  const u16* Ab0 = A + (size_t)m0 * lda + Kofs;
  const u16* Bb0 = B + (size_t)n0 * ldb + Kofs;
  f32x4 acc[4][4] = {};

  auto stage = [&](int sbuf, int kt, int part){
    u16* base = smem + sbuf * 24576;
    if (part == 0){
      const u16* Ak = Ab0 + kt * 64;
      #pragma unroll
      for (int it = 0; it < 2; ++it){
        int idx = it * 512 + tid;
        int r = idx >> 3, sl = idx & 7, g = sl ^ (r & 7);
        gl_lds16(Ak + (size_t)r * lda + g * 8, base + (it * 512 + wv * 64) * 8);
      }
      const u16* Bk = Bb0 + kt * 64;
      { int idx = tid; int r = idx >> 3, sl = idx & 7, g = sl ^ (r & 7);
        gl_lds16(Bk + (size_t)r * ldb + g * 8, base + (8192 + wv * 64 * 8)); }
    } else {
      const u16* Bk = Bb0 + kt * 64;
      #pragma unroll
      for (int it = 1; it < 4; ++it){
        int idx = it * 512 + tid;
        int r = idx >> 3, sl = idx & 7, g = sl ^ (r & 7);
        gl_lds16(Bk + (size_t)r * ldb + g * 8, base + (8192 + (it * 512 + wv * 64) * 8));
      }
    }
  };

  bf16x8 a0[4], b0[4], a1[4], b1[4];
  auto ldfrags = [&](const u16* lA, bf16x8* af, bf16x8* bf, int kk){
    const u16* lB = lA + 8192;
    #pragma unroll
    for (int mm = 0; mm < 4; mm++){
      int ra = wr * 64 + mm * 16 + l15;
      int sl = (kk * 4 + lg) ^ (ra & 7);
      af[mm] = as_bf(*(const u16x8*)&lA[(ra * 8 + sl) * 8]);
    }
    #pragma unroll
    for (int nn = 0; nn < 4; nn++){
      int cb = wc * 64 + nn * 16 + l15;
      int sl = (kk * 4 + lg) ^ (cb & 7);
      bf[nn] = as_bf(*(const u16x8*)&lB[(cb * 8 + sl) * 8]);
    }
  };
  auto mfma16 = [&](bf16x8* af, bf16x8* bf){
    __builtin_amdgcn_s_setprio(1);
    #pragma unroll
    for (int mm = 0; mm < 4; mm++)
      #pragma unroll
      for (int nn = 0; nn < 4; nn++)
        acc[mm][nn] = __builtin_amdgcn_mfma_f32_16x16x32_bf16(af[mm], bf[nn], acc[mm][nn], 0, 0, 0);
    __builtin_amdgcn_s_setprio(0);
  };

  const int nk = Klen / 64;
  stage(0, 0, 0); stage(0, 0, 1);
  stage(1, 1, 0); stage(1, 1, 1);
  asm volatile("s_waitcnt vmcnt(6)" ::: "memory");
  asm volatile("s_barrier" ::: "memory");
  ldfrags(smem, a0, b0, 0);

  for (int kt = 0; kt < nk; ++kt){
    const u16* lA = smem + (kt % 3) * 24576;
    ldfrags(lA, a1, b1, 1);
    if (kt + 2 < nk) stage((kt + 2) % 3, kt + 2, 0);
    mfma16(a0, b0);
    if (kt + 2 < nk)      asm volatile("s_waitcnt vmcnt(3)" ::: "memory");
    else if (kt + 1 < nk) asm volatile("s_waitcnt vmcnt(0)" ::: "memory");
    asm volatile("s_barrier" ::: "memory");
    if (kt + 1 < nk)
      ldfrags(smem + ((kt + 1) % 3) * 24576, a0, b0, 0);
    if (kt + 2 < nk) stage((kt + 2) % 3, kt + 2, 1);
    mfma16(a1, b1);
    asm volatile("s_barrier" ::: "memory");
  }
  #pragma unroll
  for (int mm = 0; mm < 4; mm++)
    #pragma unroll
    for (int nn = 0; nn < 4; nn++){
      int grow0 = m0 + wr * 64 + mm * 16 + lg * 4;
      int gcol  = n0 + wc * 64 + nn * 16 + l15;
      #pragma unroll
      for (int r = 0; r < 4; r++){
        float v = acc[mm][nn][r];
        if (F32OUT) ((float*)Cv + blockIdx.z * zstride)[(size_t)(grow0 + r) * ldc + gcol] = v;
        else        ((u16*)Cv)[(size_t)(grow0 + r) * ldc + gcol] = f2bf(v);
      }
    }
}

// ---------------- fp32 add (split-K reduce) ----------------
__global__ void add_f32(const float* __restrict__ a, const float* __restrict__ b,
                        float* __restrict__ o, int n4){
  int i = blockIdx.x * blockDim.x + threadIdx.x;
  if (i < n4){
    float4 x = ((const float4*)a)[i], y = ((const float4*)b)[i];
    float4 z = { x.x + y.x, x.y + y.y, x.z + y.z, x.w + y.w };
    ((float4*)o)[i] = z;
  }
}

// ---------------- RMSNorm + RoPE for Q and K; one wave per (token, head-slot) ----------------
__global__ void rmsnorm_rope(const u16* __restrict__ QKV, const int* __restrict__ pos,
                             const float* __restrict__ qw, const float* __restrict__ kw,
                             u16* __restrict__ Qr, u16* __restrict__ Kr){
  int gw = (blockIdx.x * blockDim.x + threadIdx.x) >> 6;
  int ln = threadIdx.x & 63;
  int t = gw / 24, idx = gw % 24;         // 16 Q heads + 8 K heads
  if (t >= TT) return;
  bool isq = idx < NH;
  int head = isq ? idx : idx - NH;
  const u16* src = QKV + (size_t)t * 4096 + (isq ? head * HD : 2048 + head * HD);
  const float* wgt = isq ? qw : kw;
  float x0 = bf2f(src[ln]), x1 = bf2f(src[ln + 64]);
  float ss = x0 * x0 + x1 * x1;
  #pragma unroll
  for (int off = 32; off; off >>= 1) ss += __shfl_xor(ss, off);
  float r = rsqrtf(ss * (1.0f / 128.0f) + 1e-6f);
  float xn0 = x0 * r * wgt[ln], xn1 = x1 * r * wgt[ln + 64];
  float inv = exp2f(-(float)ln * 0.311430758895690f);  // log2(1e6)/64
  float ang = (float)pos[t] * inv;
  float c = cosf(ang), s = sinf(ang);
  float o0 = xn0 * c - xn1 * s;
  float o1 = xn1 * c + xn0 * s;
  u16* dst = isq ? (Qr + (size_t)t * 2048 + head * HD) : (Kr + (size_t)t * 1024 + head * HD);
  dst[ln]      = f2bf(o0);
  dst[ln + 64] = f2bf(o1);
}

// ---------------- V transpose: QKV[t][3072 + kh*128 + d] -> Vt[kh][d][t] ----------------
__global__ void v_transpose(const u16* __restrict__ QKV, u16* __restrict__ Vt){
  __shared__ u16 tile[64][72];
  int kh = blockIdx.z;
  int d0 = blockIdx.y * 64;
  int t0 = blockIdx.x * 64;
  int tid = threadIdx.x;
  #pragma unroll
  for (int it = 0; it < 2; ++it){
    int idx = it * 256 + tid;          // 0..511
    int tr = idx >> 3, seg = idx & 7;
    *(u16x8*)&tile[tr][seg * 8] =
      *(const u16x8*)(QKV + (size_t)(t0 + tr) * 4096 + 3072 + kh * HD + d0 + seg * 8);
  }
  __syncthreads();
  #pragma unroll
  for (int it = 0; it < 2; ++it){
    int idx = it * 256 + tid;
    int dr = idx >> 3, seg = idx & 7;
    u16x8 v;
    #pragma unroll
    for (int j = 0; j < 8; j++) v[j] = tile[seg * 8 + j][dr];
    *(u16x8*)(Vt + ((size_t)kh * HD + d0 + dr) * 2048 + t0 + seg * 8) = v;
  }
}

// ---------------- causal GQA flash attention: P-double-buffered, ONE barrier/iter ----------------
// 512 threads = 8 waves: 0-3 S-role (QK^T+softmax+P write), 4-7 PV-role (PV+row-sum).
// role = wv&3 -> (qw = role&1, jp = role>>1); wave (qw,jp): q rows [64qc+32qw,+32),
// 32-tok tiles t = 2i+jp. P is DOUBLE-BUFFERED: S writes P[j&1], PV reads P[(j-1)&1]
// => the R10 mid-barrier + lgkm fence are gone; ONE __syncthreads per iteration.
// P layout [2buf][4role][32q][32tok] with even-XOR 8B-slot swizzle (slot^((q5&3)<<1)).
// QK^T split into two independent 4-MFMA chains (halves dependency depth).
// LDS = K 32KB + V 32KB + P 16KB = 81920B exactly => 2 blocks/CU.
__global__ __launch_bounds__(512, 4) void attn(const u16* __restrict__ Qr, const u16* __restrict__ Kr,
                                               const u16* __restrict__ Vt, u16* __restrict__ O){
  extern __shared__ u16 smem[];
  u16* Karea = smem;                   // [2][64tok*128d] u16
  u16* Varea = smem + 16384;           // [2][128d*64tok] u16
  u16* Parea = smem + 32768;           // [2buf][4role][32q][32tok] u16
  const int h = blockIdx.y, kh = h >> 1;
  const int qc = (h < 8) ? blockIdx.x : 31 - blockIdx.x;
  const int tid = threadIdx.x, wv = tid >> 6, ln = tid & 63;
  const bool isS = wv < 4;
  const int role = wv & 3;
  const int qw = role & 1, jp = role >> 1;
  const int q5 = ln & 31, hb = ln >> 5;
  const int nit = qc + 1;
  const int xr = (q5 & 3) << 1;        // even XOR for P slot swizzle

  auto stage = [&](int i){
    if (i + 1 < nit){                          // K for iter i+1 -> buf (i+1)&1
      u16* Kd = Karea + ((i + 1) & 1) * 8192;
      #pragma unroll
      for (int j = 0; j < 2; ++j){
        int lin = j * 512 + tid;
        int tok = lin >> 4, seg = lin & 15;
        gl_lds16(Kr + (size_t)((i + 1) * 64 + tok) * 1024 + kh * HD + (seg ^ (tok & 7)) * 8,
                 Kd + (j * 512 + wv * 64) * 8);
      }
    }
    if (i < nit){                              // V for iter i -> buf i&1 (used at i+1)
      u16* Vd = Varea + (i & 1) * 8192;
      #pragma unroll
      for (int j = 0; j < 2; ++j){
        int lin = j * 512 + tid;
        int d = lin >> 3, sl = lin & 7;
        gl_lds16(Vt + (size_t)kh * HD * 2048 + (size_t)d * 2048 + i * 64 + (sl ^ (d & 7)) * 8,
                 Vd + (j * 512 + wv * 64) * 8);
      }
    }
  };

  // prestage K[0] into buf 0
  #pragma unroll
  for (int j = 0; j < 2; ++j){
    int lin = j * 512 + tid;
    int tok = lin >> 4, seg = lin & 15;
    gl_lds16(Kr + (size_t)tok * 1024 + kh * HD + (seg ^ (tok & 7)) * 8,
             Karea + (j * 512 + wv * 64) * 8);
  }

  const u16x8 ones_u = {0x3f80, 0x3f80, 0x3f80, 0x3f80, 0x3f80, 0x3f80, 0x3f80, 0x3f80};
  const bf16x8 onesf = as_bf(ones_u);

  if (isS){
    // ---------------- S role: QK^T (2 chains) + static-max softmax + P write ----------------
    bf16x8 qf[8];
    {
      const u16* qp = Qr + (size_t)(qc * 64 + qw * 32 + q5) * 2048 + h * HD + hb * 8;
      #pragma unroll
      for (int s = 0; s < 8; ++s) qf[s] = as_bf(*(const u16x8*)(qp + s * 16));
    }
    for (int i = 0; i <= nit; ++i){
      __syncthreads();                         // single barrier: K[i],V[i-1],P[i-1] visible
      stage(i);
      const int t = 2 * i + jp;
      const int D0 = 32 * t - 64 * qc - 32 * qw;
      const bool act = (i < nit) && (D0 <= 0);
      if (act){
        const u16* Kb = Karea + (i & 1) * 8192;
        const int tokIdx = 32 * jp + q5;
        f32x16 ca = {}, cb = {};
        __builtin_amdgcn_s_setprio(1);
        #pragma unroll
        for (int s = 0; s < 4; ++s){
          int seg = (2 * s + hb) ^ (q5 & 7);
          bf16x8 kf = as_bf(*(const u16x8*)&Kb[tokIdx * 128 + seg * 8]);
          ca = __builtin_amdgcn_mfma_f32_32x32x16_bf16(kf, qf[s], ca, 0, 0, 0);
        }
        #pragma unroll
        for (int s = 4; s < 8; ++s){
          int seg = (2 * s + hb) ^ (q5 & 7);
          bf16x8 kf = as_bf(*(const u16x8*)&Kb[tokIdx * 128 + seg * 8]);
          cb = __builtin_amdgcn_mfma_f32_32x32x16_bf16(kf, qf[s], cb, 0, 0, 0);
        }
        __builtin_amdgcn_s_setprio(0);
        f32x16 c = ca + cb;
        const bool diag = (D0 == 0);
        u32 pk[8];
        #pragma unroll
        for (int j = 0; j < 8; ++j){
          float pv[2];
          #pragma unroll
          for (int e = 0; e < 2; ++e){
            int r = 2 * j + e;
            int tok = (r & 3) + 8 * (r >> 2) + 4 * hb;
            float x = c[r] * SCALE_L2E - SM_M2;
            if (diag && tok > q5) x = -1e30f;
            pv[e] = exp2f(x);
          }
          pk[j] = (__builtin_bit_cast(u32, pv[0]) >> 16) |
                  (__builtin_bit_cast(u32, pv[1]) & 0xffff0000u);
        }
        u16* Pq = Parea + (i & 1) * 4096 + role * 1024 + q5 * 32;
        *(u32x2*)&Pq[((hb + 0) ^ xr) * 4] = u32x2{pk[0], pk[1]};   // toks 4hb+0..3
        *(u32x2*)&Pq[((hb + 2) ^ xr) * 4] = u32x2{pk[2], pk[3]};   // toks 8+4hb..
        *(u32x2*)&Pq[((hb + 4) ^ xr) * 4] = u32x2{pk[4], pk[5]};
        *(u32x2*)&Pq[((hb + 6) ^ xr) * 4] = u32x2{pk[6], pk[7]};
      }
    }
    __syncthreads();                           // match PV epilogue barriers
    __syncthreads();
  } else {
    // ---------------- PV role: P (prev iter, other buf) x V + row-sum ----------------
    f32x16 acc[4] = {};
    f32x16 asum = {};
    for (int i = 0; i <= nit; ++i){
      __syncthreads();                         // single barrier
      stage(i);
      const int t = 2 * (i - 1) + jp;
      const int D0 = 32 * t - 64 * qc - 32 * qw;
      const bool act = (i >= 1) && (D0 <= 0);
      if (act){
        const u16* Pq = Parea + ((i - 1) & 1) * 4096 + role * 1024 + q5 * 32;
        bf16x8 pf0 = as_bf(*(const u16x8*)&Pq[((2 * hb + 0) ^ xr) * 4]);  // toks 8hb..+7
        bf16x8 pf1 = as_bf(*(const u16x8*)&Pq[((2 * hb + 4) ^ xr) * 4]);  // toks 16+8hb..+7
        const u16* Vb = Varea + ((i - 1) & 1) * 8192;
        __builtin_amdgcn_s_setprio(1);
        asum = __builtin_amdgcn_mfma_f32_32x32x16_bf16(pf0, onesf, asum, 0, 0, 0);
        asum = __builtin_amdgcn_mfma_f32_32x32x16_bf16(pf1, onesf, asum, 0, 0, 0);
        #pragma unroll
        for (int dblk = 0; dblk < 4; ++dblk){
          int d = dblk * 32 + q5;
          bf16x8 v0 = as_bf(*(const u16x8*)&Vb[d * 64 + ((4 * jp + 0 + hb) ^ (d & 7)) * 8]);
          bf16x8 v1 = as_bf(*(const u16x8*)&Vb[d * 64 + ((4 * jp + 2 + hb) ^ (d & 7)) * 8]);
          acc[dblk] = __builtin_amdgcn_mfma_f32_32x32x16_bf16(pf0, v0, acc[dblk], 0, 0, 0);
          acc[dblk] = __builtin_amdgcn_mfma_f32_32x32x16_bf16(pf1, v1, acc[dblk], 0, 0, 0);
        }
        __builtin_amdgcn_s_setprio(0);
      }
    }
    // ---- epilogue: combine jp parities in LDS (reuse K/V area), write O ----
    __syncthreads();
    float* Ls  = (float*)smem;                 // [2 qw][32 q][128 d] f32 = 32KB
    float* LsS = (float*)smem + 8192;          // [2 qw][32 q] row sums
    if (jp == 1){
      #pragma unroll
      for (int dblk = 0; dblk < 4; ++dblk)
        #pragma unroll
        for (int r = 0; r < 16; ++r){
          int qrow = (r & 3) + 8 * (r >> 2) + 4 * hb;
          Ls[qw * 4096 + qrow * 128 + dblk * 32 + q5] = acc[dblk][r];
        }
      if (q5 == 0){
        #pragma unroll
        for (int r = 0; r < 16; ++r){
          int qrow = (r & 3) + 8 * (r >> 2) + 4 * hb;
          LsS[qw * 32 + qrow] = asum[r];
        }
      }
    }
    __syncthreads();
    if (jp == 0){
      #pragma unroll
      for (int r = 0; r < 16; ++r){
        int qrow = (r & 3) + 8 * (r >> 2) + 4 * hb;
        float rs = 1.0f / (asum[r] + LsS[qw * 32 + qrow]);
        int qg = qc * 64 + qw * 32 + qrow;
        #pragma unroll
        for (int dblk = 0; dblk < 4; ++dblk){
          float o = (acc[dblk][r] + Ls[qw * 4096 + qrow * 128 + dblk * 32 + q5]) * rs;
          O[(size_t)qg * 2048 + h * HD + dblk * 32 + q5] = f2bf(o);
        }
      }
    }
  }
}

extern "C" void kernel_launch(void* const* d_in, const int* in_sizes, int n_in,
                              void* d_out, int out_size, void* d_ws, size_t ws_size,
                              hipStream_t stream){
  const int*   positions = (const int*)d_in[0];
  const float* hidden    = (const float*)d_in[1];
  const float* wq        = (const float*)d_in[2];
  const float* wk        = (const float*)d_in[3];
  const float* wv        = (const float*)d_in[4];
  const float* wo        = (const float*)d_in[5];
  const float* qw        = (const float*)d_in[6];
  const float* kw        = (const float*)d_in[7];
  float* out = (float*)d_out;

  char* ws = (char*)d_ws;
  u16* hs   = (u16*)ws; ws += (size_t)2048 * 2048 * 2;
  u16* Wqkv = (u16*)ws; ws += (size_t)4096 * 2048 * 2;   // [4096][2048] = Wq^T | Wk^T | Wv^T
  u16* Wo   = (u16*)ws; ws += (size_t)2048 * 2048 * 2;   // [2048][2048] = wo^T
  u16* QKV  = (u16*)ws; ws += (size_t)2048 * 4096 * 2;   // [T][4096]
  u16* Qr   = (u16*)ws; ws += (size_t)2048 * 2048 * 2;   // [T][16][128]
  u16* Kr   = (u16*)ws; ws += (size_t)2048 * 1024 * 2;   // [T][8][128]
  u16* Vt   = (u16*)ws; ws += (size_t)8 * 128 * 2048 * 2; // [8][128][T]
  u16* O    = (u16*)ws;                                   // [T][2048]

  cast_f32_bf16<<<2048, 256, 0, stream>>>(hidden, hs, 2048 * 2048 / 8);
  transpose_cast<<<dim3(32, 32), 256, 0, stream>>>(wq, Wqkv, 2048, 2048);
  transpose_cast<<<dim3(16, 32), 256, 0, stream>>>(wk, Wqkv + (size_t)2048 * 2048, 2048, 1024);
  transpose_cast<<<dim3(16, 32), 256, 0, stream>>>(wv, Wqkv + (size_t)3072 * 2048, 2048, 1024);
  transpose_cast<<<dim3(32, 32), 256, 0, stream>>>(wo, Wo, 2048, 2048);

  // QKV = hs @ [Wq|Wk|Wv] : M=2048, N=4096, K=2048 ; 256 blocks, 144KB LDS, 1 blk/CU
  gemm8p<false><<<dim3(16, 16, 1), 512, 147456, stream>>>(hs, Wqkv, QKV, 2048, 2048, 2048, 4096, 0);

  rmsnorm_rope<<<2048 * 24 / 4, 256, 0, stream>>>(QKV, positions, qw, kw, Qr, Kr);
  v_transpose<<<dim3(32, 2, 8), 256, 0, stream>>>(QKV, Vt);

  // attention: 512 blocks x 512 threads, 81920B LDS (exactly 80KB) => 2 blocks/CU
  attn<<<dim3(32, 16), 512, 81920, stream>>>(Qr, Kr, Vt, O);

  // out = O @ wo : split-K=2 (256 blocks), fp32 partials overlay dead QKV region
  float* p0 = (float*)QKV;
  gemm8p<true><<<dim3(8, 16, 2), 512, 147456, stream>>>(O, Wo, p0, 1024, 2048, 2048, 2048,
                                                        (size_t)2048 * 2048);
  add_f32<<<4096, 256, 0, stream>>>(p0, p0 + (size_t)2048 * 2048, out, 2048 * 2048 / 4);
}